// Round 6
// baseline (29.344 us; speedup 1.0000x reference)
//
#include <hip/hip_runtime.h>
#include <math.h>

// ListNet segment-softmax CE, sorted week indices.
// BATCH = 4194304, NUM_WEEKS = 262144, avg 16 items/week.
//
// Per-week loss = T/S_l - log(S_s);  S_l = sum e^l, S_s = sum e^s, T = sum e^l*s.
// (eps inside log dropped; validated rounds 2-5, absmax 0.0)
//
// Round-6: r5's serial-walk kept; loads fixed. r5 had 64B-stride dwordx4
// loads (64 cachelines/instr). Now each block stages 2048-item halves into
// LDS with coalesced 16B/lane loads; XOR swizzle p = s ^ ((s>>3)&7) on f4
// slots makes BOTH the write pattern (s=j*256+t) and the thread-contiguous
// read pattern (s=2t+k) hit all 8 bank-quads per 8 lanes -> no LDS conflict
// penalty. Each thread walks 8 contiguous items per half: interior runs
// finalized in registers; head/tail runs -> LDS slot atomics (w - w0);
// block-interior slots finalized locally; 2 boundary records per block.

#define TPB 256
#define CHUNK 4096        // items per block
#define HALF 2048         // items per staging phase
#define HF4 512           // float4 slots per phase per array
#define SLOTS 768         // max span+1 (~256 expected, 32-sigma margin)

__device__ __forceinline__ int swz(int s) { return s ^ ((s >> 3) & 7); }

__device__ __forceinline__ void lds_flush(float* lel, float* les, float* ltl,
                                          int* lcnt, int s, float a, float b,
                                          float t, int c) {
    atomicAdd(&lel[s], a);
    atomicAdd(&les[s], b);
    atomicAdd(&ltl[s], t);
    atomicAdd(&lcnt[s], c);
}

__global__ __launch_bounds__(TPB) void main_pass(
        const float* __restrict__ scores, const float* __restrict__ labels,
        const int* __restrict__ widx,
        int* __restrict__ rec_week, float* __restrict__ rec_el,
        float* __restrict__ rec_es, float* __restrict__ rec_tl,
        int* __restrict__ rec_cnt,
        float* __restrict__ part_loss, int* __restrict__ part_nv) {
    __shared__ int4   stg_w[HF4];
    __shared__ float4 stg_l[HF4];
    __shared__ float4 stg_s[HF4];
    __shared__ float lel[SLOTS], les[SLOTS], ltl[SLOTS];
    __shared__ int lcnt[SLOTS];
    const int tid = threadIdx.x;
    for (int s = tid; s < SLOTS; s += TPB) {
        lel[s] = 0.f; les[s] = 0.f; ltl[s] = 0.f; lcnt[s] = 0;
    }
    const int base = blockIdx.x * CHUNK;
    const int w0 = widx[base];
    const int wl = widx[base + CHUNK - 1];

    float loss = 0.f; int nv = 0;

    #pragma unroll
    for (int h = 0; h < 2; ++h) {
        const int hbase = base + h * HALF;
        __syncthreads();   // staging buffer free (init done / prev walk done)
        #pragma unroll
        for (int j = 0; j < 2; ++j) {
            const int s = j * TPB + tid;           // coalesced: lane-contiguous
            const int p = swz(s);
            stg_w[p] = *reinterpret_cast<const int4*>(widx + hbase + s * 4);
            stg_l[p] = *reinterpret_cast<const float4*>(labels + hbase + s * 4);
            stg_s[p] = *reinterpret_cast<const float4*>(scores + hbase + s * 4);
        }
        __syncthreads();

        // thread walks its 8 contiguous items (f4 slots 2*tid, 2*tid+1)
        const int p0 = swz(2 * tid), p1 = swz(2 * tid + 1);
        const int4   wA = stg_w[p0], wB = stg_w[p1];
        const float4 lA = stg_l[p0], lB = stg_l[p1];
        const float4 sA = stg_s[p0], sB = stg_s[p1];

        int cw; float ra, rb, rt; int rc;
        bool head_saved = false;
        int hs = 0; float ha = 0.f, hb = 0.f, ht = 0.f; int hc = 0;
        {
            const float el = __expf(lA.x), es = __expf(sA.x);
            cw = wA.x; ra = el; rb = es; rt = el * sA.x; rc = 1;
        }
#define ITEM(wv, lv, sv)                                                       \
    {                                                                          \
        const float el = __expf(lv), es = __expf(sv);                          \
        if ((wv) == cw) { ra += el; rb += es; rt += el * (sv); ++rc; }         \
        else {                                                                 \
            if (!head_saved) {                                                 \
                hs = cw - w0; ha = ra; hb = rb; ht = rt; hc = rc;              \
                head_saved = true;                                             \
            } else if (rc >= 2) {                                              \
                loss += rt / ra - __logf(rb); ++nv;  /* thread-complete week */\
            }                                                                  \
            cw = (wv); ra = el; rb = es; rt = el * (sv); rc = 1;               \
        }                                                                      \
    }
        ITEM(wA.y, lA.y, sA.y) ITEM(wA.z, lA.z, sA.z) ITEM(wA.w, lA.w, sA.w)
        ITEM(wB.x, lB.x, sB.x) ITEM(wB.y, lB.y, sB.y) ITEM(wB.z, lB.z, sB.z)
        ITEM(wB.w, lB.w, sB.w)
#undef ITEM
        // boundary runs of this thread's 8-item window -> LDS slots
        if (head_saved) lds_flush(lel, les, ltl, lcnt, hs, ha, hb, ht, hc);
        lds_flush(lel, les, ltl, lcnt, cw - w0, ra, rb, rt, rc);
    }
    __syncthreads();

    // block-interior slots (strictly between w0 and wl) are complete here
    const int span = wl - w0;
    for (int s = 1 + tid; s < span; s += TPB) {
        const int c = lcnt[s];
        if (c >= 2) { loss += ltl[s] / lel[s] - __logf(les[s]); ++nv; }
    }
    #pragma unroll
    for (int off = 32; off; off >>= 1) {
        loss += __shfl_down(loss, off);
        nv   += __shfl_down(nv, off);
    }
    __shared__ float ra4[4];
    __shared__ int   rn4[4];
    const int lane = tid & 63, wv4 = tid >> 6;
    if (lane == 0) { ra4[wv4] = loss; rn4[wv4] = nv; }
    __syncthreads();
    if (tid == 0) {
        part_loss[blockIdx.x] = ra4[0] + ra4[1] + ra4[2] + ra4[3];
        part_nv[blockIdx.x]   = rn4[0] + rn4[1] + rn4[2] + rn4[3];
        const int b2 = blockIdx.x * 2;
        rec_week[b2] = w0;
        rec_el[b2] = lel[0]; rec_es[b2] = les[0];
        rec_tl[b2] = ltl[0]; rec_cnt[b2] = lcnt[0];
        rec_week[b2 + 1] = wl;
        if (span > 0) {
            rec_el[b2 + 1] = lel[span]; rec_es[b2 + 1] = les[span];
            rec_tl[b2 + 1] = ltl[span]; rec_cnt[b2 + 1] = lcnt[span];
        } else {  // single-week block: zero filler keeps run-adjacency intact
            rec_el[b2 + 1] = 0.f; rec_es[b2 + 1] = 0.f;
            rec_tl[b2 + 1] = 0.f; rec_cnt[b2 + 1] = 0;
        }
    }
}

__global__ __launch_bounds__(1024) void finalize(
        const int* __restrict__ rec_week, const float* __restrict__ rec_el,
        const float* __restrict__ rec_es, const float* __restrict__ rec_tl,
        const int* __restrict__ rec_cnt,
        const float* __restrict__ part_loss, const int* __restrict__ part_nv,
        int nrec, int nb, float* __restrict__ out) {
    const int tid = threadIdx.x;
    float loss = 0.f; int nv = 0;
    for (int j = tid; j < nrec; j += 1024) {
        const int w = rec_week[j];
        if (j > 0 && rec_week[j - 1] == w) continue;  // not a run head
        float a = rec_el[j], b = rec_es[j], t = rec_tl[j];
        int c = rec_cnt[j];
        int k = j + 1;
        while (k < nrec && rec_week[k] == w) {
            a += rec_el[k]; b += rec_es[k]; t += rec_tl[k]; c += rec_cnt[k]; ++k;
        }
        if (c >= 2) { loss += t / a - __logf(b); ++nv; }
    }
    for (int j = tid; j < nb; j += 1024) { loss += part_loss[j]; nv += part_nv[j]; }
    #pragma unroll
    for (int off = 32; off; off >>= 1) {
        loss += __shfl_down(loss, off);
        nv   += __shfl_down(nv, off);
    }
    __shared__ float ra[16];
    __shared__ int   rn[16];
    const int lane = tid & 63, wv = tid >> 6;
    if (lane == 0) { ra[wv] = loss; rn[wv] = nv; }
    __syncthreads();
    if (tid == 0) {
        float tl = 0.f; int tn = 0;
        for (int k = 0; k < 16; ++k) { tl += ra[k]; tn += rn[k]; }
        out[0] = (tn > 0) ? (-tl / (float)tn) : 0.f;
    }
}

extern "C" void kernel_launch(void* const* d_in, const int* in_sizes, int n_in,
                              void* d_out, int out_size, void* d_ws, size_t ws_size,
                              hipStream_t stream) {
    const float* scores = (const float*)d_in[0];
    const float* labels = (const float*)d_in[1];
    const int*   widx   = (const int*)d_in[2];
    const int n  = in_sizes[0];
    const int nb = n / CHUNK;      // 1024
    const int nrec = nb * 2;

    char* ws = (char*)d_ws;
    size_t off = 0;
    int*   rec_week = (int*)  (ws + off); off += (size_t)nrec * 4;
    float* rec_el   = (float*)(ws + off); off += (size_t)nrec * 4;
    float* rec_es   = (float*)(ws + off); off += (size_t)nrec * 4;
    float* rec_tl   = (float*)(ws + off); off += (size_t)nrec * 4;
    int*   rec_cnt  = (int*)  (ws + off); off += (size_t)nrec * 4;
    float* part_loss= (float*)(ws + off); off += (size_t)nb * 4;
    int*   part_nv  = (int*)  (ws + off);

    float* out = (float*)d_out;

    main_pass<<<nb, TPB, 0, stream>>>(scores, labels, widx,
                                      rec_week, rec_el, rec_es, rec_tl, rec_cnt,
                                      part_loss, part_nv);
    finalize<<<1, 1024, 0, stream>>>(rec_week, rec_el, rec_es, rec_tl, rec_cnt,
                                     part_loss, part_nv, nrec, nb, out);
}